// Round 5
// baseline (81.789 us; speedup 1.0000x reference)
//
#include <hip/hip_runtime.h>
#include <hip/hip_bf16.h>

typedef unsigned short u16;
typedef __attribute__((ext_vector_type(8))) __bf16 bf16x8;
typedef __attribute__((ext_vector_type(4))) float f32x4;
typedef __attribute__((ext_vector_type(4))) unsigned short u16x4;
typedef __attribute__((ext_vector_type(4))) unsigned int u32x4;

#define DEV static __device__ __forceinline__

static constexpr int N = 2048, D = 1024;
static constexpr float EPS = 1e-5f;

DEV u16 f2b(float f) {
  union { float f; unsigned u; } x; x.f = f;
  unsigned r = x.u + 0x7FFFu + ((x.u >> 16) & 1u);   // RNE
  return (u16)(r >> 16);
}
DEV float b2f(u16 h) {
  union { unsigned u; float f; } x; x.u = ((unsigned)h) << 16;
  return x.f;
}

DEV void async16(const void* g, void* l) {
  __builtin_amdgcn_global_load_lds(
      (const __attribute__((address_space(1))) unsigned int*)g,
      (__attribute__((address_space(3))) unsigned int*)l, 16, 0, 0);
}

// ---- fused pre: blocks [0,2048) = LayerNorm(x)->bf16 AND out=x; [2048,6144) = transpose w -> bf16 [N][K]
__global__ __launch_bounds__(256) void k_pre(const float* __restrict__ x,
                                             const float* __restrict__ wq, const float* __restrict__ wk,
                                             const float* __restrict__ wv, const float* __restrict__ wo,
                                             u16* __restrict__ xn, u16* __restrict__ wt,
                                             float* __restrict__ out) {
  const int t = threadIdx.x;
  if (blockIdx.x < 2048) {
    const int row = blockIdx.x;
    const float4 v = ((const float4*)(x + (size_t)row * D))[t];
    ((float4*)(out + (size_t)row * D))[t] = v;      // residual base; rows<256 get atomic adds later
    float s  = v.x + v.y + v.z + v.w;
    float ss = v.x * v.x + v.y * v.y + v.z * v.z + v.w * v.w;
    __shared__ float red0[4], red1[4];
    for (int off = 32; off; off >>= 1) { s += __shfl_xor(s, off, 64); ss += __shfl_xor(ss, off, 64); }
    const int w = t >> 6, l = t & 63;
    if (l == 0) { red0[w] = s; red1[w] = ss; }
    __syncthreads();
    s  = red0[0] + red0[1] + red0[2] + red0[3];
    ss = red1[0] + red1[1] + red1[2] + red1[3];
    const float mu = s * (1.0f / D);
    const float var = ss * (1.0f / D) - mu * mu;
    const float rs = rsqrtf(var + EPS);
    u16x4 o;
    o.x = f2b((v.x - mu) * rs); o.y = f2b((v.y - mu) * rs);
    o.z = f2b((v.z - mu) * rs); o.w = f2b((v.w - mu) * rs);
    ((u16x4*)(xn + (size_t)row * D))[t] = o;
  } else {
    const int bid = blockIdx.x - 2048;
    const int z = bid >> 10, rem = bid & 1023;
    const float* src = z == 0 ? wq : z == 1 ? wk : z == 2 ? wv : wo;
    u16* dst = wt + (size_t)z * D * D;
    __shared__ float tile[32][33];
    const int k0 = (rem >> 5) * 32, n0 = (rem & 31) * 32;
    const int c = t & 31, r4 = t >> 5;
#pragma unroll
    for (int p = 0; p < 4; ++p) { int r = r4 + p * 8; tile[r][c] = src[(size_t)(k0 + r) * D + n0 + c]; }
    __syncthreads();
#pragma unroll
    for (int p = 0; p < 4; ++p) { int r = r4 + p * 8; dst[(size_t)(n0 + r) * D + k0 + c] = f2b(tile[c][r]); }
  }
}

// ---- shared LDS block for gemm64 (hoisted so template instantiations share one allocation) ----
struct GemmShared {
  u16 As[2][128 * 32];     // 16 KB, chunk-XOR swizzled
  u16 Bs[2][64 * 32];      //  8 KB, chunk-XOR swizzled
  float red_s[128][2];     //  1 KB (EPI==1 only)
  float red_ss[128][2];    //  1 KB
};

// 128x64 bf16 MFMA GEMM tile, double-buffered, K-range [kbeg,kend).
// LDS layout swizzle: 16B chunk c of row r stored at chunk c^(r&3)  (both-sides: pre-swizzled
// global source for global_load_lds + XOR'd ds_read addr; rule #21).
// EPI: 1 = per-row LN over the 64 cols -> bf16 store; 2 = bf16 store; 3 = f32 atomicAdd
template<int EPI>
DEV void gemm64(GemmShared& sh, const u16* __restrict__ A, const u16* __restrict__ BT,
                void* __restrict__ dst, int row0, int col0, int dcol0, int ldc, int kbeg, int kend) {
  constexpr int K = 1024, BK = 32;
  const int t = threadIdx.x;
  const int w = t >> 6, l = t & 63;
  const int wm = (w & 1) << 6, wn = (w >> 1) << 5;

  f32x4 acc[4][2];
#pragma unroll
  for (int i = 0; i < 4; ++i)
#pragma unroll
    for (int j = 0; j < 2; ++j) acc[i][j] = (f32x4){0.f, 0.f, 0.f, 0.f};

  const int sr = t >> 2;                       // staged row 0..63; LDS dest byte = t*16 (wave-linear)
  const int scg = ((t & 3) ^ (sr & 3)) << 3;   // pre-swizzled global k-chunk (u16 units)
  const u16* gA0 = A + (size_t)(row0 + sr) * K + scg;
  const u16* gA1 = gA0 + (size_t)64 * K;       // (sr+64)&3 == sr&3, same swizzle
  const u16* gB0 = BT + (size_t)(col0 + sr) * K + scg;
  u16* lA0 = &sh.As[0][0] + t * 8;             // u16 units; byte t*16
  u16* lA1 = lA0 + 64 * BK;
  u16* lB0 = &sh.Bs[0][0] + t * 8;
  constexpr int ABUF = 128 * BK, BBUF = 64 * BK;

  const int fr = l & 15;          // A-row / B-col within 16x16 frag
  const int kg = l >> 4;          // k-chunk group 0..3 (8 u16 each)

  // prologue: stage first tile into buf 0
  async16(gA0 + kbeg, lA0);
  async16(gA1 + kbeg, lA1);
  async16(gB0 + kbeg, lB0);
  __syncthreads();

  int cur = 0;
  for (int k0 = kbeg; k0 < kend; k0 += BK) {
    const int nxt = k0 + BK;
    if (nxt < kend) {                          // stage next tile into other buffer
      const int o = (cur ^ 1);
      async16(gA0 + nxt, lA0 + o * ABUF);
      async16(gA1 + nxt, lA1 + o * ABUF);
      async16(gB0 + nxt, lB0 + o * BBUF);
    }
    bf16x8 af[4], bf[2];
#pragma unroll
    for (int i = 0; i < 4; ++i) {
      const int R = wm + i * 16 + fr;
      af[i] = *(const bf16x8*)&sh.As[cur][R * BK + ((kg ^ (R & 3)) << 3)];
    }
#pragma unroll
    for (int j = 0; j < 2; ++j) {
      const int R = wn + j * 16 + fr;
      bf[j] = *(const bf16x8*)&sh.Bs[cur][R * BK + ((kg ^ (R & 3)) << 3)];
    }
#pragma unroll
    for (int i = 0; i < 4; ++i)
#pragma unroll
      for (int j = 0; j < 2; ++j)
        acc[i][j] = __builtin_amdgcn_mfma_f32_16x16x32_bf16(af[i], bf[j], acc[i][j], 0, 0, 0);
    __syncthreads();   // drains: next-tile loads visible, this-tile LDS reads done
    cur ^= 1;
  }

  const int rq = (l >> 4) << 2;
  if constexpr (EPI == 1) {
    // per-row LN over 64 cols: C/D layout col=fr, row=wm+i*16+rq+r; cols split j(2) x fr(16) x wave-half(2)
    float ps[4][4], pss[4][4];
#pragma unroll
    for (int i = 0; i < 4; ++i)
#pragma unroll
      for (int r = 0; r < 4; ++r) {
        const float a = acc[i][0][r], b = acc[i][1][r];
        ps[i][r] = a + b; pss[i][r] = a * a + b * b;
      }
    for (int off = 1; off < 16; off <<= 1)
#pragma unroll
      for (int i = 0; i < 4; ++i)
#pragma unroll
        for (int r = 0; r < 4; ++r) {
          ps[i][r]  += __shfl_xor(ps[i][r],  off, 16);
          pss[i][r] += __shfl_xor(pss[i][r], off, 16);
        }
    if (fr == 0) {
#pragma unroll
      for (int i = 0; i < 4; ++i)
#pragma unroll
        for (int r = 0; r < 4; ++r) {
          const int R = wm + i * 16 + rq + r;
          sh.red_s[R][w >> 1]  = ps[i][r];
          sh.red_ss[R][w >> 1] = pss[i][r];
        }
    }
    __syncthreads();
    u16* o = (u16*)dst;
#pragma unroll
    for (int i = 0; i < 4; ++i)
#pragma unroll
      for (int r = 0; r < 4; ++r) {
        const int R = wm + i * 16 + rq + r;
        const float S  = sh.red_s[R][0] + sh.red_s[R][1];
        const float SS = sh.red_ss[R][0] + sh.red_ss[R][1];
        const float mu = S * (1.0f / 64);
        const float rs = rsqrtf(SS * (1.0f / 64) - mu * mu + EPS);
#pragma unroll
        for (int j = 0; j < 2; ++j)
          o[(size_t)(row0 + R) * ldc + dcol0 + wn + j * 16 + fr] = f2b((acc[i][j][r] - mu) * rs);
      }
  } else if constexpr (EPI == 2) {
    u16* o = (u16*)dst;
#pragma unroll
    for (int i = 0; i < 4; ++i)
#pragma unroll
      for (int j = 0; j < 2; ++j)
#pragma unroll
        for (int r = 0; r < 4; ++r)
          o[(size_t)(row0 + wm + i * 16 + rq + r) * ldc + dcol0 + wn + j * 16 + fr] = f2b(acc[i][j][r]);
  } else {
    float* o = (float*)dst;
#pragma unroll
    for (int i = 0; i < 4; ++i)
#pragma unroll
      for (int j = 0; j < 2; ++j)
#pragma unroll
        for (int r = 0; r < 4; ++r)
          atomicAdd(&o[(size_t)(row0 + wm + i * 16 + rq + r) * ldc + dcol0 + wn + j * 16 + fr],
                    acc[i][j][r]);
  }
}

// fused QKV: [0,512) kv GEMM (M=2048, N=2048 over [wk|wv]^T), LN-fused for k, bf16 for v;
//            [512,544) q GEMM (M=256, N=1024), LN-fused
__global__ __launch_bounds__(256) void k_gemm_qkv(const u16* __restrict__ xn, const u16* __restrict__ wt,
                                                  u16* __restrict__ qh, u16* __restrict__ kh,
                                                  u16* __restrict__ vh) {
  __shared__ GemmShared sh;
  const int bid = blockIdx.x;
  if (bid < 512) {
    const int r0 = (bid >> 5) * 128, c0 = (bid & 31) * 64;
    const u16* BT = wt + (size_t)D * D;   // [wk^T | wv^T] contiguous, 2048 rows
    if (c0 < 1024) gemm64<1>(sh, xn, BT, kh, r0, c0, c0, D, 0, 1024);
    else           gemm64<2>(sh, xn, BT, vh, r0, c0, c0 - 1024, D, 0, 1024);
  } else {
    const int q = bid - 512;
    gemm64<1>(sh, xn, wt, qh, (q >> 4) * 128, (q & 15) * 64, (q & 15) * 64, D, 0, 1024);
  }
}

// output GEMM split-K(4): out[m][n] += sum_k attnb[m][k] * wo[k][n], rows<256
__global__ __launch_bounds__(256) void k_gemm_o(const u16* __restrict__ attnb, const u16* __restrict__ wt,
                                                float* __restrict__ out) {
  __shared__ GemmShared sh;
  const int tile = blockIdx.x & 31, s = blockIdx.x >> 5;
  gemm64<3>(sh, attnb, wt + (size_t)3 * D * D, out,
            (tile >> 4) * 128, (tile & 15) * 64, (tile & 15) * 64, D, s * 256, s * 256 + 256);
}

// ---- block-sparse attention: block = (head h, q-block b); kv rows {b+16j} (all bf16 inputs) ----
__global__ __launch_bounds__(256) void k_attn(const u16* __restrict__ qh, const u16* __restrict__ kh,
                                              const u16* __restrict__ vh, u16* __restrict__ attnb) {
  const int h = blockIdx.x >> 4, b = blockIdx.x & 15;
  __shared__ float q_s[16][68];
  __shared__ u16  k_u[128][72];                 // 144B row stride: 16B-aligned, conflict-light
  __shared__ u16  v_u[128][64];
  __shared__ float s_s[16][132];
  __shared__ float inv_den[16];
  const int t = threadIdx.x;

  {
    const int i = t >> 4, sub = t & 15;
    const u16x4 qq = *(const u16x4*)&qh[(size_t)(b * 16 + i) * D + h * 64 + sub * 4];
    q_s[i][sub * 4 + 0] = b2f(qq.x); q_s[i][sub * 4 + 1] = b2f(qq.y);
    q_s[i][sub * 4 + 2] = b2f(qq.z); q_s[i][sub * 4 + 3] = b2f(qq.w);
  }
#pragma unroll
  for (int it = 0; it < 4; ++it) {
    const int idx = t + it * 256;               // 1024 chunks of 8 u16 = 128 rows x 8
    const int j = idx >> 3, c = (idx & 7) * 8;
    const int kr = b + 16 * j;
    *(u32x4*)&k_u[j][c] = *(const u32x4*)&kh[(size_t)kr * D + h * 64 + c];
    *(u32x4*)&v_u[j][c] = *(const u32x4*)&vh[(size_t)kr * D + h * 64 + c];
  }
  __syncthreads();

  const int i = t >> 4;
  const int sub = t & 15;
#pragma unroll
  for (int jj = 0; jj < 8; ++jj) {
    const int j = sub + 16 * jj;
    float acc = 0.f;
#pragma unroll
    for (int d4 = 0; d4 < 16; ++d4) {
      const u16x4 kk = *(const u16x4*)&k_u[j][d4 * 4];
      acc += q_s[i][d4 * 4 + 0] * b2f(kk.x) + q_s[i][d4 * 4 + 1] * b2f(kk.y)
           + q_s[i][d4 * 4 + 2] * b2f(kk.z) + q_s[i][d4 * 4 + 3] * b2f(kk.w);
    }
    s_s[i][j] = acc * 0.125f;   // sm_scale = 1/sqrt(64)
  }
  __syncthreads();
  float m = -1e30f;
#pragma unroll
  for (int jj = 0; jj < 8; ++jj) m = fmaxf(m, s_s[i][sub + 16 * jj]);
  for (int off = 1; off < 16; off <<= 1) m = fmaxf(m, __shfl_xor(m, off, 64));
  float sum = 0.f;
#pragma unroll
  for (int jj = 0; jj < 8; ++jj) {
    const int j = sub + 16 * jj;
    const float p = __expf(s_s[i][j] - m);
    s_s[i][j] = p;
    sum += p;
  }
  for (int off = 1; off < 16; off <<= 1) sum += __shfl_xor(sum, off, 64);
  if (sub == 0) inv_den[i] = 1.0f / sum;
  __syncthreads();

  const int db = sub << 2;
  float a0 = 0, a1 = 0, a2 = 0, a3 = 0;
  for (int j = 0; j < 128; ++j) {
    const float p = s_s[i][j];
    const u16x4 vv = *(const u16x4*)&v_u[j][db];
    a0 += p * b2f(vv.x); a1 += p * b2f(vv.y); a2 += p * b2f(vv.z); a3 += p * b2f(vv.w);
  }
  const float inv = inv_den[i];
  u16x4 o;
  o.x = f2b(a0 * inv); o.y = f2b(a1 * inv); o.z = f2b(a2 * inv); o.w = f2b(a3 * inv);
  *(u16x4*)&attnb[(size_t)(b * 16 + i) * D + h * 64 + db] = o;
}

extern "C" void kernel_launch(void* const* d_in, const int* in_sizes, int n_in,
                              void* d_out, int out_size, void* d_ws, size_t ws_size,
                              hipStream_t stream) {
  const float* x  = (const float*)d_in[0];
  const float* wq = (const float*)d_in[1];
  const float* wk = (const float*)d_in[2];
  const float* wv = (const float*)d_in[3];
  const float* wo = (const float*)d_in[4];
  float* out = (float*)d_out;
  char* ws = (char*)d_ws;

  // ws layout (~21 MiB)
  u16* xn    = (u16*)(ws + 0);           // [2048][1024] bf16 LN(x)
  u16* wt    = (u16*)(ws + 4194304);     // [4][1024][1024] bf16 w^T (q,k,v,o)
  u16* qh    = (u16*)(ws + 12582912);    // [256][1024]  bf16 per-head-LN q
  u16* kh    = (u16*)(ws + 13107200);    // [2048][1024] bf16 per-head-LN k
  u16* vh    = (u16*)(ws + 17301504);    // [2048][1024] bf16 v
  u16* attnb = (u16*)(ws + 21495808);    // [256][1024]  bf16 attn output

  k_pre<<<dim3(6144), dim3(256), 0, stream>>>(x, wq, wk, wv, wo, xn, wt, out);
  k_gemm_qkv<<<dim3(544), dim3(256), 0, stream>>>(xn, wt, qh, kh, vh);
  k_attn<<<dim3(256), dim3(256), 0, stream>>>(qh, kh, vh, attnb);
  k_gemm_o<<<dim3(128), dim3(256), 0, stream>>>(attnb, wt, out);
}

// Round 6
// 53.887 us; speedup vs baseline: 1.5178x; 1.5178x over previous
//
#include <hip/hip_runtime.h>
#include <hip/hip_bf16.h>

typedef unsigned short u16;
typedef __attribute__((ext_vector_type(8))) __bf16 bf16x8;
typedef __attribute__((ext_vector_type(4))) float f32x4;
typedef __attribute__((ext_vector_type(4))) unsigned short u16x4;
typedef __attribute__((ext_vector_type(4))) unsigned int u32x4;

#define DEV static __device__ __forceinline__

static constexpr int N = 2048, D = 1024;
static constexpr float EPS = 1e-5f;

DEV u16 f2b(float f) {
  union { float f; unsigned u; } x; x.f = f;
  unsigned r = x.u + 0x7FFFu + ((x.u >> 16) & 1u);   // RNE
  return (u16)(r >> 16);
}
DEV float b2f(u16 h) {
  union { unsigned u; float f; } x; x.u = ((unsigned)h) << 16;
  return x.f;
}

DEV void async16(const void* g, void* l) {
  __builtin_amdgcn_global_load_lds(
      (const __attribute__((address_space(1))) unsigned int*)g,
      (__attribute__((address_space(3))) unsigned int*)l, 16, 0, 0);
}

// ---- fused pre: blocks [0,2048) = LayerNorm(x)->bf16 AND out=x; [2048,6144) = transpose w -> bf16 [N][K]
__global__ __launch_bounds__(256) void k_pre(const float* __restrict__ x,
                                             const float* __restrict__ wq, const float* __restrict__ wk,
                                             const float* __restrict__ wv, const float* __restrict__ wo,
                                             u16* __restrict__ xn, u16* __restrict__ wt,
                                             float* __restrict__ out) {
  const int t = threadIdx.x;
  if (blockIdx.x < 2048) {
    const int row = blockIdx.x;
    const float4 v = ((const float4*)(x + (size_t)row * D))[t];
    ((float4*)(out + (size_t)row * D))[t] = v;      // residual base; rows<256 get atomic adds later
    float s  = v.x + v.y + v.z + v.w;
    float ss = v.x * v.x + v.y * v.y + v.z * v.z + v.w * v.w;
    __shared__ float red0[4], red1[4];
    for (int off = 32; off; off >>= 1) { s += __shfl_xor(s, off, 64); ss += __shfl_xor(ss, off, 64); }
    const int w = t >> 6, l = t & 63;
    if (l == 0) { red0[w] = s; red1[w] = ss; }
    __syncthreads();
    s  = red0[0] + red0[1] + red0[2] + red0[3];
    ss = red1[0] + red1[1] + red1[2] + red1[3];
    const float mu = s * (1.0f / D);
    const float var = ss * (1.0f / D) - mu * mu;
    const float rs = rsqrtf(var + EPS);
    u16x4 o;
    o.x = f2b((v.x - mu) * rs); o.y = f2b((v.y - mu) * rs);
    o.z = f2b((v.z - mu) * rs); o.w = f2b((v.w - mu) * rs);
    ((u16x4*)(xn + (size_t)row * D))[t] = o;
  } else {
    const int bid = blockIdx.x - 2048;
    const int z = bid >> 10, rem = bid & 1023;
    const float* src = z == 0 ? wq : z == 1 ? wk : z == 2 ? wv : wo;
    u16* dst = wt + (size_t)z * D * D;
    __shared__ float tile[32][33];
    const int k0 = (rem >> 5) * 32, n0 = (rem & 31) * 32;
    const int c = t & 31, r4 = t >> 5;
#pragma unroll
    for (int p = 0; p < 4; ++p) { int r = r4 + p * 8; tile[r][c] = src[(size_t)(k0 + r) * D + n0 + c]; }
    __syncthreads();
#pragma unroll
    for (int p = 0; p < 4; ++p) { int r = r4 + p * 8; dst[(size_t)(n0 + r) * D + k0 + c] = f2b(tile[c][r]); }
  }
}

// ---- shared LDS for gemm64 (one allocation shared across template instantiations) ----
struct GS { u16 As[64 * 64]; u16 Bs[64 * 64]; };   // 16 KB

// 64x64 bf16 MFMA GEMM tile, BK=64, K-range [kbeg,kend).
// LDS swizzle: 16B chunk c of row R stored at chunk c^(R&7)  (both-sides: pre-swizzled global
// source for global_load_lds, XOR'd ds_read addr). Spreads 16 consecutive rows across all 8
// bank-quads -> 2-way (free) instead of 16-way conflict on the b128 frag reads.
// EPI: 1 = per-row LN over the 64 cols -> bf16; 2 = bf16 store; 3 = f32 atomicAdd
template<int EPI>
DEV void gemm64(GS& sh, const u16* __restrict__ A, const u16* __restrict__ BT,
                void* __restrict__ dst, int row0, int col0, int dcol0, int ldc,
                int kbeg, int kend) {
  constexpr int K = 1024, BK = 64;
  const int t = threadIdx.x;
  const int w = t >> 6, l = t & 63;
  const int wm = w << 4;                 // wave's 16 output rows
  const int fr = l & 15, kg = l >> 4;
  const int rq = kg << 2;

  f32x4 acc[4];
#pragma unroll
  for (int j = 0; j < 4; ++j) acc[j] = (f32x4){0.f, 0.f, 0.f, 0.f};

  // staging: 512 chunks (16B) per panel; thread t handles chunks t and t+256.
  // chunk c -> row c>>3, stored chunk-pos c&7, fetched from global chunk (c&7)^(row&7).
  const int r0s = t >> 3,          cs0 = (t & 7) ^ (r0s & 7);
  const int r1s = (t + 256) >> 3,  cs1 = (t & 7) ^ (r1s & 7);   // (t+256)&7 == t&7
  const u16* gA0 = A  + (size_t)(row0 + r0s) * K + cs0 * 8;
  const u16* gA1 = A  + (size_t)(row0 + r1s) * K + cs1 * 8;
  const u16* gB0 = BT + (size_t)(col0 + r0s) * K + cs0 * 8;
  const u16* gB1 = BT + (size_t)(col0 + r1s) * K + cs1 * 8;
  u16* lA0 = &sh.As[t * 8];
  u16* lA1 = &sh.As[(t + 256) * 8];
  u16* lB0 = &sh.Bs[t * 8];
  u16* lB1 = &sh.Bs[(t + 256) * 8];

  for (int k0 = kbeg; k0 < kend; k0 += BK) {
    async16(gA0 + k0, lA0);
    async16(gA1 + k0, lA1);
    async16(gB0 + k0, lB0);
    async16(gB1 + k0, lB1);
    __syncthreads();                       // drain vmcnt: staged data visible
    bf16x8 af[2], bf[4][2];
#pragma unroll
    for (int kk = 0; kk < 2; ++kk)
      af[kk] = *(const bf16x8*)&sh.As[(wm + fr) * BK + ((kk * 4 + kg) ^ (fr & 7)) * 8];
#pragma unroll
    for (int j = 0; j < 4; ++j)
#pragma unroll
      for (int kk = 0; kk < 2; ++kk)
        bf[j][kk] = *(const bf16x8*)&sh.Bs[(j * 16 + fr) * BK + ((kk * 4 + kg) ^ (fr & 7)) * 8];
#pragma unroll
    for (int kk = 0; kk < 2; ++kk)
#pragma unroll
      for (int j = 0; j < 4; ++j)
        acc[j] = __builtin_amdgcn_mfma_f32_16x16x32_bf16(af[kk], bf[j][kk], acc[j], 0, 0, 0);
    __syncthreads();                       // LDS reads done before next stage overwrites
  }

  // C/D layout: col = j*16 + fr, row = wm + rq + r
  if constexpr (EPI == 1) {
    // per-row LN over this tile's 64 cols (tile == one head). Row's 64 cols live in
    // the 16 lanes sharing rq (fr=0..15) x 4 j-frags -> width-16 shuffle reduce.
    float ps[4], pss[4];
#pragma unroll
    for (int r = 0; r < 4; ++r) {
      float s = 0.f, ss = 0.f;
#pragma unroll
      for (int j = 0; j < 4; ++j) { const float v = acc[j][r]; s += v; ss += v * v; }
      ps[r] = s; pss[r] = ss;
    }
    for (int off = 1; off < 16; off <<= 1)
#pragma unroll
      for (int r = 0; r < 4; ++r) {
        ps[r]  += __shfl_xor(ps[r],  off, 16);
        pss[r] += __shfl_xor(pss[r], off, 16);
      }
    u16* o = (u16*)dst;
#pragma unroll
    for (int r = 0; r < 4; ++r) {
      const float mu = ps[r] * (1.0f / 64);
      const float rs = rsqrtf(pss[r] * (1.0f / 64) - mu * mu + EPS);
      const int row = row0 + wm + rq + r;
#pragma unroll
      for (int j = 0; j < 4; ++j)
        o[(size_t)row * ldc + dcol0 + j * 16 + fr] = f2b((acc[j][r] - mu) * rs);
    }
  } else if constexpr (EPI == 2) {
    u16* o = (u16*)dst;
#pragma unroll
    for (int r = 0; r < 4; ++r) {
      const int row = row0 + wm + rq + r;
#pragma unroll
      for (int j = 0; j < 4; ++j)
        o[(size_t)row * ldc + dcol0 + j * 16 + fr] = f2b(acc[j][r]);
    }
  } else {
    float* o = (float*)dst;
#pragma unroll
    for (int r = 0; r < 4; ++r) {
      const int row = row0 + wm + rq + r;
#pragma unroll
      for (int j = 0; j < 4; ++j)
        atomicAdd(&o[(size_t)row * ldc + dcol0 + j * 16 + fr], acc[j][r]);
    }
  }
}

// fused QKV: [0,1024) kv GEMM 64x64 tiles (M=2048, N=2048 over [wk|wv]^T): LN->kh / bf16->vh;
//            [1024,1088) q GEMM (M=256, N=1024): LN->qh
__global__ __launch_bounds__(256) void k_gemm_qkv(const u16* __restrict__ xn, const u16* __restrict__ wt,
                                                  u16* __restrict__ qh, u16* __restrict__ kh,
                                                  u16* __restrict__ vh) {
  __shared__ GS sh;
  const int bid = blockIdx.x;
  if (bid < 1024) {
    const int r0 = (bid >> 5) * 64, c0 = (bid & 31) * 64;
    const u16* BT = wt + (size_t)D * D;       // [wk^T | wv^T], 2048 rows
    if (c0 < 1024) gemm64<1>(sh, xn, BT, kh, r0, c0, c0, D, 0, 1024);
    else           gemm64<2>(sh, xn, BT, vh, r0, c0, c0 - 1024, D, 0, 1024);
  } else {
    const int q = bid - 1024;
    gemm64<1>(sh, xn, wt, qh, (q >> 4) * 64, (q & 15) * 64, (q & 15) * 64, D, 0, 1024);
  }
}

// output GEMM: 64 tiles (4x16 of 64x64) x split-K(2, slices of 512) -> atomicAdd into out (rows<256)
__global__ __launch_bounds__(256) void k_gemm_o(const u16* __restrict__ attnb, const u16* __restrict__ wt,
                                                float* __restrict__ out) {
  __shared__ GS sh;
  const int s = blockIdx.x & 1, tile = blockIdx.x >> 1;
  gemm64<3>(sh, attnb, wt + (size_t)3 * D * D, out,
            (tile >> 4) * 64, (tile & 15) * 64, (tile & 15) * 64, D, s * 512, s * 512 + 512);
}

// ---- block-sparse attention: block = (head h, q-block b); kv rows {b+16j} (all bf16 inputs) ----
__global__ __launch_bounds__(256) void k_attn(const u16* __restrict__ qh, const u16* __restrict__ kh,
                                              const u16* __restrict__ vh, u16* __restrict__ attnb) {
  const int h = blockIdx.x >> 4, b = blockIdx.x & 15;
  __shared__ float q_s[16][68];
  __shared__ u16  k_u[128][72];                 // 144B row stride: 16B-aligned, conflict-light
  __shared__ u16  v_u[128][64];
  __shared__ float s_s[16][132];
  __shared__ float inv_den[16];
  const int t = threadIdx.x;

  {
    const int i = t >> 4, sub = t & 15;
    const u16x4 qq = *(const u16x4*)&qh[(size_t)(b * 16 + i) * D + h * 64 + sub * 4];
    q_s[i][sub * 4 + 0] = b2f(qq.x); q_s[i][sub * 4 + 1] = b2f(qq.y);
    q_s[i][sub * 4 + 2] = b2f(qq.z); q_s[i][sub * 4 + 3] = b2f(qq.w);
  }
#pragma unroll
  for (int it = 0; it < 4; ++it) {
    const int idx = t + it * 256;               // 1024 chunks of 8 u16 = 128 rows x 8
    const int j = idx >> 3, c = (idx & 7) * 8;
    const int kr = b + 16 * j;
    *(u32x4*)&k_u[j][c] = *(const u32x4*)&kh[(size_t)kr * D + h * 64 + c];
    *(u32x4*)&v_u[j][c] = *(const u32x4*)&vh[(size_t)kr * D + h * 64 + c];
  }
  __syncthreads();

  const int i = t >> 4;
  const int sub = t & 15;
#pragma unroll
  for (int jj = 0; jj < 8; ++jj) {
    const int j = sub + 16 * jj;
    float acc = 0.f;
#pragma unroll
    for (int d4 = 0; d4 < 16; ++d4) {
      const u16x4 kk = *(const u16x4*)&k_u[j][d4 * 4];
      acc += q_s[i][d4 * 4 + 0] * b2f(kk.x) + q_s[i][d4 * 4 + 1] * b2f(kk.y)
           + q_s[i][d4 * 4 + 2] * b2f(kk.z) + q_s[i][d4 * 4 + 3] * b2f(kk.w);
    }
    s_s[i][j] = acc * 0.125f;   // sm_scale = 1/sqrt(64)
  }
  __syncthreads();
  float m = -1e30f;
#pragma unroll
  for (int jj = 0; jj < 8; ++jj) m = fmaxf(m, s_s[i][sub + 16 * jj]);
  for (int off = 1; off < 16; off <<= 1) m = fmaxf(m, __shfl_xor(m, off, 64));
  float sum = 0.f;
#pragma unroll
  for (int jj = 0; jj < 8; ++jj) {
    const int j = sub + 16 * jj;
    const float p = __expf(s_s[i][j] - m);
    s_s[i][j] = p;
    sum += p;
  }
  for (int off = 1; off < 16; off <<= 1) sum += __shfl_xor(sum, off, 64);
  if (sub == 0) inv_den[i] = 1.0f / sum;
  __syncthreads();

  const int db = sub << 2;
  float a0 = 0, a1 = 0, a2 = 0, a3 = 0;
  for (int j = 0; j < 128; ++j) {
    const float p = s_s[i][j];
    const u16x4 vv = *(const u16x4*)&v_u[j][db];
    a0 += p * b2f(vv.x); a1 += p * b2f(vv.y); a2 += p * b2f(vv.z); a3 += p * b2f(vv.w);
  }
  const float inv = inv_den[i];
  u16x4 o;
  o.x = f2b(a0 * inv); o.y = f2b(a1 * inv); o.z = f2b(a2 * inv); o.w = f2b(a3 * inv);
  *(u16x4*)&attnb[(size_t)(b * 16 + i) * D + h * 64 + db] = o;
}

extern "C" void kernel_launch(void* const* d_in, const int* in_sizes, int n_in,
                              void* d_out, int out_size, void* d_ws, size_t ws_size,
                              hipStream_t stream) {
  const float* x  = (const float*)d_in[0];
  const float* wq = (const float*)d_in[1];
  const float* wk = (const float*)d_in[2];
  const float* wv = (const float*)d_in[3];
  const float* wo = (const float*)d_in[4];
  float* out = (float*)d_out;
  char* ws = (char*)d_ws;

  // ws layout (~21 MiB)
  u16* xn    = (u16*)(ws + 0);           // [2048][1024] bf16 LN(x)
  u16* wt    = (u16*)(ws + 4194304);     // [4][1024][1024] bf16 w^T (q,k,v,o)
  u16* qh    = (u16*)(ws + 12582912);    // [256][1024]  bf16 per-head-LN q
  u16* kh    = (u16*)(ws + 13107200);    // [2048][1024] bf16 per-head-LN k
  u16* vh    = (u16*)(ws + 17301504);    // [2048][1024] bf16 v
  u16* attnb = (u16*)(ws + 21495808);    // [256][1024]  bf16 attn output

  k_pre<<<dim3(6144), dim3(256), 0, stream>>>(x, wq, wk, wv, wo, xn, wt, out);
  k_gemm_qkv<<<dim3(1088), dim3(256), 0, stream>>>(xn, wt, qh, kh, vh);
  k_attn<<<dim3(256), dim3(256), 0, stream>>>(qh, kh, vh, attnb);
  k_gemm_o<<<dim3(128), dim3(256), 0, stream>>>(attnb, wt, out);
}